// Round 2
// baseline (248.076 us; speedup 1.0000x reference)
//
#include <hip/hip_runtime.h>
#include <hip/hip_bf16.h>

// CTC loss, fp32 in / fp32 out. T=1024, B=32, C=1024, L=128 fixed.
// R6: fp64 meet-in-the-middle DP (absmax 0.0) + register-rotation prefetch
//     (distance 3) of emissions from LDS; per-step chain is shfl(a3) + 3
//     dependent f64 ops (~31 cyc).
// R7: emit_kernel early-exits rows t >= data_length[b] (-5.3 us, matched model).
// R8: combine_kernel folded into dp_kernel via last-block-done reduction
//     (emit zeroes a ws counter; dp blocks __threadfence + atomicAdd; the
//     64th arriver acquires and runs the combine inline). Removes one
//     dispatch + one launch gap + the cold-start latency of a 1-block
//     kernel. Summation grouping replicated exactly -> bitwise-identical
//     output (absmax must stay 0.0).
#define T_DIM 1024
#define B_DIM 32
#define C_DIM 1024
#define L_DIM 128
#define S_DIM 257
#define CH    32          // timesteps per staged chunk

// ---- workspace layout (bytes) ----
#define WS_EPAIR   0                                  // [B][T][64] float2 = 16 MiB
#define WS_EBLANK  (32u * 1024u * 64u * 8u)           // [B][T] float
#define WS_ALPHA   (WS_EBLANK + 32u * 1024u * 4u)     // [B][264] double
#define WS_BETA    (WS_ALPHA + 32u * 264u * 8u)       // [B][264] double (257,258 = 0)
#define WS_KACC    (WS_BETA + 32u * 264u * 8u)        // [B][2] long long
#define WS_CNT     (WS_KACC + 32u * 2u * 8u)          // 1 unsigned

// ---------------- Kernel 1: log-softmax + linear emission gather ----------------
__global__ __launch_bounds__(256) void emit_kernel(const float* __restrict__ data,
                                                   const int* __restrict__ labels,
                                                   const int* __restrict__ data_length,
                                                   float2* __restrict__ epair,
                                                   float* __restrict__ eblank,
                                                   unsigned* __restrict__ cnt) {
    // R8: re-init the dp completion counter each iteration (ws is poisoned).
    if (blockIdx.x == 0 && threadIdx.x == 0) *cnt = 0u;

    const int wave = threadIdx.x >> 6;
    const int lane = threadIdx.x & 63;
    const int row = blockIdx.x * 4 + wave;           // row = t*B + b
    const int b = row & (B_DIM - 1);
    const int t = row >> 5;                          // B = 32

    // R7: rows past this example's data_length are never read by the DP.
    if (t >= data_length[b]) return;

    const float4* d4 = (const float4*)(data + (size_t)row * C_DIM);
    float4 v[4];
    float m = -3.4e38f;
#pragma unroll
    for (int k = 0; k < 4; ++k) {
        v[k] = d4[lane + 64 * k];
        m = fmaxf(m, fmaxf(fmaxf(v[k].x, v[k].y), fmaxf(v[k].z, v[k].w)));
    }
#pragma unroll
    for (int off = 32; off >= 1; off >>= 1)
        m = fmaxf(m, __shfl_xor(m, off, 64));
    float s = 0.f;
#pragma unroll
    for (int k = 0; k < 4; ++k)
        s += __expf(v[k].x - m) + __expf(v[k].y - m) +
             __expf(v[k].z - m) + __expf(v[k].w - m);
#pragma unroll
    for (int off = 32; off >= 1; off >>= 1)
        s += __shfl_xor(s, off, 64);
    const float lse = m + __logf(s);

    const float* drow = data + (size_t)row * C_DIM;
    const int2 cc = ((const int2*)(labels + b * L_DIM))[lane];   // labels 2l, 2l+1
    float2 pr;
    pr.x = __expf(drow[cc.x] - lse);
    pr.y = __expf(drow[cc.y] - lse);
    epair[((size_t)b * T_DIM + t) * 64 + lane] = pr;             // b-major rows
    if (lane == 0) eblank[b * T_DIM + t] = __expf(drow[0] - lse);
}

// ---------------- Kernel 2: alpha/beta DP (fp64 linear, prefetched) ----------------
// grid = 64 blocks: b = blockIdx&31, dir = blockIdx>>5 (0=fwd alpha, 1=bwd beta).
// One wave per block. Lane l owns 4 states; one shfl_up(a3) per step.
// R8: the last-finishing block also performs the combine (see tail).
__global__ __launch_bounds__(64, 1) void dp_kernel(const float2* __restrict__ epair,
                                                   const float* __restrict__ eblank,
                                                   const int* __restrict__ labels,
                                                   const int* __restrict__ label_length,
                                                   const int* __restrict__ data_length,
                                                   double* __restrict__ alphavec,
                                                   double* __restrict__ betavec,
                                                   long long* __restrict__ kaccs,
                                                   unsigned* __restrict__ cnt,
                                                   float* __restrict__ out) {
    const int b   = blockIdx.x & (B_DIM - 1);
    const int dir = blockIdx.x >> 5;
    const int l = threadIdx.x;
    const int* lab = labels + b * L_DIM;
    const int len = label_length[b];
    const int dlen = data_length[b];
    const int m = dlen >> 1;          // split point: alpha(m-1) meets beta(m)

    __shared__ float2 ebuf[2][CH][64];   // 32 KiB double buffer
    __shared__ float  ebl[T_DIM];        // whole blank row, 4 KiB

    const float2* eprow = epair + (size_t)b * T_DIM * 64;
    const float*  ebrow = eblank + (size_t)b * T_DIM;

    // Stage entire blank row: 16 x (64 lanes x 4 B). Rows t >= dlen may hold
    // poison (emit skips them) but are never consumed arithmetically.
#pragma unroll
    for (int i = 0; i < T_DIM / 64; ++i)
        __builtin_amdgcn_global_load_lds(
            (const __attribute__((address_space(1))) void*)(ebrow + i * 64 + l),
            (__attribute__((address_space(3))) void*)(&ebl[i * 64]), 4, 0, 0);

    // Stage CH epair rows [trow0, trow0+CH) : 16 x (64 lanes x 16 B), 2 rows/instr.
    auto stage_chunk = [&](int cb, int trow0) {
#pragma unroll
        for (int i = 0; i < CH / 2; ++i)
            __builtin_amdgcn_global_load_lds(
                (const __attribute__((address_space(1))) void*)
                    ((const char*)(eprow + (size_t)(trow0 + 2 * i) * 64) + l * 16),
                (__attribute__((address_space(3))) void*)(&ebuf[cb][2 * i][0]), 16, 0, 0);
    };

    double a0 = 0.0, a1 = 0.0, a2 = 0.0, a3 = 0.0, a4 = 0.0;
    long long kacc = 0;

    // em1 multiplies state 4l+1, em3 multiplies state 4l+3 (fwd: ep.x/ep.y;
    // bwd reversed: ep.y/ep.x). skip1d/skip3d set per-direction below.
    double skip1d, skip3d;
    auto step = [&](double em1, double em3, double eb) {
        double h = __shfl_up(a3, 1, 64);
        if (l == 0) h = 0.0;
        const double n0 = (a0 + h) * eb;
        const double n1 = fma(skip1d, h, a1 + a0) * em1;
        const double n2 = (a2 + a1) * eb;
        const double n3 = fma(skip3d, a1, a3 + a2) * em3;
        const double n4 = (a4 + a3) * eb;
        a0 = n0; a1 = n1; a2 = n2; a3 = n3; a4 = n4;
    };

    auto renorm = [&]() {
        double mx = fmax(fmax(fmax(a0, a1), fmax(a2, a3)), a4);
        int hi = __double2hiint(mx);            // alphas >= 0: hi-word order = value order
#pragma unroll
        for (int off = 32; off >= 1; off >>= 1)
            hi = max(hi, __shfl_xor(hi, off, 64));
        const int ex = ((hi >> 20) & 0x7ff) - 1023;
        const double sc = __hiloint2double((1023 - ex) << 20, 0);   // 2^-ex
        a0 *= sc; a1 *= sc; a2 *= sc; a3 *= sc; a4 *= sc;
        kacc += ex;
    };

    if (dir == 0) {
        // ---------------- forward alpha: t = 0 .. m-1 ----------------
        const int2 cc = ((const int2*)lab)[l];                        // labels 2l, 2l+1
        skip1d = ((l > 0) && (cc.x != lab[2 * l - 1])) ? 1.0 : 0.0;
        skip3d = (cc.y != cc.x) ? 1.0 : 0.0;

        stage_chunk(0, 1);
        __builtin_amdgcn_s_waitcnt(0x0f70);     // vmcnt(0)

        {   // t = 0 init
            const float2 ep0 = eprow[l];
            a0 = (l == 0) ? (double)ebl[0] : 0.0;
            a1 = (l == 0) ? (double)ep0.x : 0.0;
        }

        const int nsteps = m - 1;               // t = 1 .. m-1
        const int nch = (nsteps + CH - 1) / CH;
        for (int c = 0; c < nch; ++c) {
            const int cb = c & 1;
            const bool more = (c + 1 < nch);
            if (more) stage_chunk(cb ^ 1, 1 + CH * (c + 1));
            __builtin_amdgcn_sched_barrier(0);
            const int t0 = 1 + CH * c;
            if (t0 + CH <= m) {
                // full chunk: branch-free body, distance-3 register rotation
                double e1R[4], e2R[4], ebR[4];
#pragma unroll
                for (int p = 0; p < 3; ++p) {
                    const float2 ep = ebuf[cb][p][l];
                    e1R[p] = (double)ep.x; e2R[p] = (double)ep.y;
                    ebR[p] = (double)ebl[t0 + p];
                }
#pragma unroll
                for (int j = 0; j < CH; ++j) {
                    const int jn = (j + 3 < CH) ? (j + 3) : (CH - 1);
                    const float2 epn = ebuf[cb][jn][l];
                    const float ebn = ebl[t0 + jn];
                    step(e1R[j & 3], e2R[j & 3], ebR[j & 3]);
                    e1R[(j + 3) & 3] = (double)epn.x;
                    e2R[(j + 3) & 3] = (double)epn.y;
                    ebR[(j + 3) & 3] = (double)ebn;
                }
            } else {
                // tail chunk (once): predicated, plain LDS reads
#pragma unroll
                for (int j = 0; j < CH; ++j) {
                    if (t0 + j < m) {
                        const float2 ep = ebuf[cb][j][l];
                        step((double)ep.x, (double)ep.y, (double)ebl[t0 + j]);
                    }
                }
            }
            renorm();
            if (more) __builtin_amdgcn_s_waitcnt(0x0f70);
            __builtin_amdgcn_sched_barrier(0);
        }

        double* av = alphavec + b * 264;
        av[4 * l + 0] = a0; av[4 * l + 1] = a1;
        av[4 * l + 2] = a2; av[4 * l + 3] = a3;
        if (l == 63) av[256] = a4;
        if (l == 0) kaccs[2 * b + 0] = kacc;
    } else {
        // ---------------- backward beta: t = dlen-1 .. m (reversed states r=256-s) ----
        const int2 c2 = ((const int2*)lab)[63 - l];    // (lab[126-2l], lab[127-2l])
        const int labL = (l > 0) ? lab[128 - 2 * l] : -1;
        skip1d = ((l > 0) && (labL != c2.y)) ? 1.0 : 0.0;   // r=4l+1
        skip3d = (c2.y != c2.x) ? 1.0 : 0.0;                // r=4l+3

        stage_chunk(0, dlen - 1 - CH);          // rows [dlen-1-CH, dlen-2]
        __builtin_amdgcn_s_waitcnt(0x0f70);

        {   // init at t = dlen-1: beta = e * [s==2len || s==2len-1],  s = 256-r
            const float2 epi = eprow[(size_t)(dlen - 1) * 64 + (63 - l)];
            const double ebi = (double)ebl[dlen - 1];
            const int s0 = 256 - 4 * l;
            a0 = (s0 == 2 * len     || s0 == 2 * len - 1) ? ebi : 0.0;
            a1 = (s0 - 1 == 2 * len || s0 - 1 == 2 * len - 1) ? (double)epi.y : 0.0;
            a2 = (s0 - 2 == 2 * len || s0 - 2 == 2 * len - 1) ? ebi : 0.0;
            a3 = (s0 - 3 == 2 * len || s0 - 3 == 2 * len - 1) ? (double)epi.x : 0.0;
            a4 = 0.0;                            // lane63's r=256 is s=0, never terminal
        }

        const int nsteps = dlen - 1 - m;        // t = dlen-2 .. m
        const int nch = (nsteps + CH - 1) / CH;
        for (int c = 0; c < nch; ++c) {
            const int cb = c & 1;
            const bool more = (c + 1 < nch);
            const int thi = dlen - 2 - CH * c;
            const int tlo = thi - CH + 1;
            if (more) stage_chunk(cb ^ 1, tlo - CH);
            __builtin_amdgcn_sched_barrier(0);
            if (tlo >= m) {
                // full chunk: jj ascending = t descending; em1 = ep.y, em3 = ep.x
                double e1R[4], e2R[4], ebR[4];
#pragma unroll
                for (int p = 0; p < 3; ++p) {
                    const float2 ep = ebuf[cb][CH - 1 - p][63 - l];
                    e1R[p] = (double)ep.y; e2R[p] = (double)ep.x;
                    ebR[p] = (double)ebl[thi - p];
                }
#pragma unroll
                for (int jj = 0; jj < CH; ++jj) {
                    const int jnn = (jj + 3 < CH) ? (jj + 3) : (CH - 1);
                    const float2 epn = ebuf[cb][CH - 1 - jnn][63 - l];
                    const float ebn = ebl[thi - jnn];
                    step(e1R[jj & 3], e2R[jj & 3], ebR[jj & 3]);
                    e1R[(jj + 3) & 3] = (double)epn.y;
                    e2R[(jj + 3) & 3] = (double)epn.x;
                    ebR[(jj + 3) & 3] = (double)ebn;
                }
            } else {
                // tail chunk (once): predicated
#pragma unroll
                for (int jj = 0; jj < CH; ++jj) {
                    const int j = CH - 1 - jj;
                    const int t = tlo + j;
                    if (t >= m) {
                        const float2 ep = ebuf[cb][j][63 - l];
                        step((double)ep.y, (double)ep.x, (double)ebl[t]);
                    }
                }
            }
            renorm();
            if (more) __builtin_amdgcn_s_waitcnt(0x0f70);
            __builtin_amdgcn_sched_barrier(0);
        }

        double* bv = betavec + b * 264;               // natural s order
        bv[256 - 4 * l] = a0; bv[255 - 4 * l] = a1;
        bv[254 - 4 * l] = a2; bv[253 - 4 * l] = a3;
        if (l == 63) bv[0] = a4;
        if (l == 0) { bv[257] = 0.0; bv[258] = 0.0; kaccs[2 * b + 1] = kacc; }
    }

    // ---------------- R8: last-block-done combine ----------------
    // release our alpha/beta/kacc stores, then count.
    __threadfence();
    unsigned old = 0u;
    if (l == 0) old = atomicAdd(cnt, 1u);
    old = __shfl(old, 0, 64);
    if (old == 2u * B_DIM - 1u) {
        __threadfence();   // acquire: see all other blocks' stores
        // Exactly the old combine_kernel math; summation grouping preserved
        // (part[w] = sum over b == w mod 4, then left-assoc sum) so the
        // output is bitwise identical to the 3-kernel version.
        float part[4];
#pragma unroll
        for (int w = 0; w < 4; ++w) {
            float acc = 0.f;
#pragma unroll 2
            for (int bb = w; bb < B_DIM; bb += 4) {
                const double* A  = alphavec + bb * 264;
                const double* Bv = betavec + bb * 264;
                const int* labb  = labels + bb * L_DIM;

                const double x0 = A[4 * l], x1 = A[4 * l + 1];
                const double x2 = A[4 * l + 2], x3 = A[4 * l + 3];
                const double y0 = Bv[4 * l], y1 = Bv[4 * l + 1], y2 = Bv[4 * l + 2];
                const double y3 = Bv[4 * l + 3], y4 = Bv[4 * l + 4], y5 = Bv[4 * l + 5];
                const double sk1 = (labb[2 * l + 1] != labb[2 * l]) ? 1.0 : 0.0;
                const int labn = (l < 63) ? labb[2 * l + 2] : -1;
                const double sk3 = ((l < 63) && (labn != labb[2 * l + 1])) ? 1.0 : 0.0;

                double s = x0 * (y0 + y1)
                         + x1 * (y1 + y2 + sk1 * y3)
                         + x2 * (y2 + y3)
                         + x3 * (y3 + y4 + sk3 * y5);
                if (l == 63) s += A[256] * Bv[256];

#pragma unroll
                for (int off = 32; off >= 1; off >>= 1)
                    s += __shfl_xor(s, off, 64);

                const long long k = kaccs[2 * bb] + kaccs[2 * bb + 1];
                const long long vb = __double_as_longlong(s);
                const int ve = (int)((vb >> 52) & 0x7ff) - 1023;
                const double mant = __longlong_as_double(
                    (vb & 0x000FFFFFFFFFFFFFLL) | (1023LL << 52));        // [1,2)
                const double l2 = (double)__log2f((float)mant) + (double)ve + (double)k;
                acc += (float)(-l2 * 0.6931471805599453);
            }
            part[w] = acc;
        }
        if (l == 0)
            out[0] = (part[0] + part[1] + part[2] + part[3]) * (1.0f / B_DIM);
    }
}

extern "C" void kernel_launch(void* const* d_in, const int* in_sizes, int n_in,
                              void* d_out, int out_size, void* d_ws, size_t ws_size,
                              hipStream_t stream) {
    const int*   labels       = (const int*)d_in[0];
    const float* data         = (const float*)d_in[1];
    const int*   label_length = (const int*)d_in[2];
    const int*   data_length  = (const int*)d_in[3];
    float*       out          = (float*)d_out;

    char* ws = (char*)d_ws;
    float2*    epair    = (float2*)(ws + WS_EPAIR);
    float*     eblank   = (float*)(ws + WS_EBLANK);
    double*    alphavec = (double*)(ws + WS_ALPHA);
    double*    betavec  = (double*)(ws + WS_BETA);
    long long* kaccs    = (long long*)(ws + WS_KACC);
    unsigned*  cnt      = (unsigned*)(ws + WS_CNT);

    const int rows = T_DIM * B_DIM;
    emit_kernel<<<rows / 4, 256, 0, stream>>>(data, labels, data_length, epair, eblank, cnt);
    dp_kernel<<<2 * B_DIM, 64, 0, stream>>>(epair, eblank, labels, label_length,
                                            data_length, alphavec, betavec, kaccs, cnt, out);
}

// Round 3
// 235.311 us; speedup vs baseline: 1.0542x; 1.0542x over previous
//
#include <hip/hip_runtime.h>
#include <hip/hip_bf16.h>

// CTC loss, fp32 in / fp32 out. T=1024, B=32, C=1024, L=128 fixed.
// R6: fp64 meet-in-the-middle DP (absmax 0.0) + register-rotation prefetch
//     (distance 3) of emissions from LDS; per-step chain is shfl(a3) + 3
//     dependent f64 ops (~31 cyc).
// R7: emit_kernel early-exits rows t >= data_length[b] (-5.3 us, matched model).
// R8 (REVERTED): folding combine into dp via last-block-done + device fences
//     cost +12 us — 64 blocks' __threadfence() (L2 wb/inv with dirty fills
//     resident) plus single-wave cold reads after invalidate outweigh the
//     ~6 us of combine kernel + launch gap. Kernel-boundary flush is cheaper
//     than in-kernel device-scope fences here. Back to the 3-kernel R7 form.
#define T_DIM 1024
#define B_DIM 32
#define C_DIM 1024
#define L_DIM 128
#define S_DIM 257
#define CH    32          // timesteps per staged chunk

// ---- workspace layout (bytes) ----
#define WS_EPAIR   0                                  // [B][T][64] float2 = 16 MiB
#define WS_EBLANK  (32u * 1024u * 64u * 8u)           // [B][T] float
#define WS_ALPHA   (WS_EBLANK + 32u * 1024u * 4u)     // [B][264] double
#define WS_BETA    (WS_ALPHA + 32u * 264u * 8u)       // [B][264] double (257,258 = 0)
#define WS_KACC    (WS_BETA + 32u * 264u * 8u)        // [B][2] long long

// ---------------- Kernel 1: log-softmax + linear emission gather ----------------
__global__ __launch_bounds__(256) void emit_kernel(const float* __restrict__ data,
                                                   const int* __restrict__ labels,
                                                   const int* __restrict__ data_length,
                                                   float2* __restrict__ epair,
                                                   float* __restrict__ eblank) {
    const int wave = threadIdx.x >> 6;
    const int lane = threadIdx.x & 63;
    const int row = blockIdx.x * 4 + wave;           // row = t*B + b
    const int b = row & (B_DIM - 1);
    const int t = row >> 5;                          // B = 32

    // R7: rows past this example's data_length are never read by the DP.
    if (t >= data_length[b]) return;

    const float4* d4 = (const float4*)(data + (size_t)row * C_DIM);
    float4 v[4];
    float m = -3.4e38f;
#pragma unroll
    for (int k = 0; k < 4; ++k) {
        v[k] = d4[lane + 64 * k];
        m = fmaxf(m, fmaxf(fmaxf(v[k].x, v[k].y), fmaxf(v[k].z, v[k].w)));
    }
#pragma unroll
    for (int off = 32; off >= 1; off >>= 1)
        m = fmaxf(m, __shfl_xor(m, off, 64));
    float s = 0.f;
#pragma unroll
    for (int k = 0; k < 4; ++k)
        s += __expf(v[k].x - m) + __expf(v[k].y - m) +
             __expf(v[k].z - m) + __expf(v[k].w - m);
#pragma unroll
    for (int off = 32; off >= 1; off >>= 1)
        s += __shfl_xor(s, off, 64);
    const float lse = m + __logf(s);

    const float* drow = data + (size_t)row * C_DIM;
    const int2 cc = ((const int2*)(labels + b * L_DIM))[lane];   // labels 2l, 2l+1
    float2 pr;
    pr.x = __expf(drow[cc.x] - lse);
    pr.y = __expf(drow[cc.y] - lse);
    epair[((size_t)b * T_DIM + t) * 64 + lane] = pr;             // b-major rows
    if (lane == 0) eblank[b * T_DIM + t] = __expf(drow[0] - lse);
}

// ---------------- Kernel 2: alpha/beta DP (fp64 linear, prefetched) ----------------
// grid = 64 blocks: b = blockIdx&31, dir = blockIdx>>5 (0=fwd alpha, 1=bwd beta).
// One wave per block. Lane l owns 4 states; one shfl_up(a3) per step.
__global__ __launch_bounds__(64, 1) void dp_kernel(const float2* __restrict__ epair,
                                                   const float* __restrict__ eblank,
                                                   const int* __restrict__ labels,
                                                   const int* __restrict__ label_length,
                                                   const int* __restrict__ data_length,
                                                   double* __restrict__ alphavec,
                                                   double* __restrict__ betavec,
                                                   long long* __restrict__ kaccs) {
    const int b   = blockIdx.x & (B_DIM - 1);
    const int dir = blockIdx.x >> 5;
    const int l = threadIdx.x;
    const int* lab = labels + b * L_DIM;
    const int len = label_length[b];
    const int dlen = data_length[b];
    const int m = dlen >> 1;          // split point: alpha(m-1) meets beta(m)

    __shared__ float2 ebuf[2][CH][64];   // 32 KiB double buffer
    __shared__ float  ebl[T_DIM];        // whole blank row, 4 KiB

    const float2* eprow = epair + (size_t)b * T_DIM * 64;
    const float*  ebrow = eblank + (size_t)b * T_DIM;

    // Stage entire blank row: 16 x (64 lanes x 4 B). Rows t >= dlen may hold
    // poison (emit skips them) but are never consumed arithmetically.
#pragma unroll
    for (int i = 0; i < T_DIM / 64; ++i)
        __builtin_amdgcn_global_load_lds(
            (const __attribute__((address_space(1))) void*)(ebrow + i * 64 + l),
            (__attribute__((address_space(3))) void*)(&ebl[i * 64]), 4, 0, 0);

    // Stage CH epair rows [trow0, trow0+CH) : 16 x (64 lanes x 16 B), 2 rows/instr.
    auto stage_chunk = [&](int cb, int trow0) {
#pragma unroll
        for (int i = 0; i < CH / 2; ++i)
            __builtin_amdgcn_global_load_lds(
                (const __attribute__((address_space(1))) void*)
                    ((const char*)(eprow + (size_t)(trow0 + 2 * i) * 64) + l * 16),
                (__attribute__((address_space(3))) void*)(&ebuf[cb][2 * i][0]), 16, 0, 0);
    };

    double a0 = 0.0, a1 = 0.0, a2 = 0.0, a3 = 0.0, a4 = 0.0;
    long long kacc = 0;

    // em1 multiplies state 4l+1, em3 multiplies state 4l+3 (fwd: ep.x/ep.y;
    // bwd reversed: ep.y/ep.x). skip1d/skip3d set per-direction below.
    double skip1d, skip3d;
    auto step = [&](double em1, double em3, double eb) {
        double h = __shfl_up(a3, 1, 64);
        if (l == 0) h = 0.0;
        const double n0 = (a0 + h) * eb;
        const double n1 = fma(skip1d, h, a1 + a0) * em1;
        const double n2 = (a2 + a1) * eb;
        const double n3 = fma(skip3d, a1, a3 + a2) * em3;
        const double n4 = (a4 + a3) * eb;
        a0 = n0; a1 = n1; a2 = n2; a3 = n3; a4 = n4;
    };

    auto renorm = [&]() {
        double mx = fmax(fmax(fmax(a0, a1), fmax(a2, a3)), a4);
        int hi = __double2hiint(mx);            // alphas >= 0: hi-word order = value order
#pragma unroll
        for (int off = 32; off >= 1; off >>= 1)
            hi = max(hi, __shfl_xor(hi, off, 64));
        const int ex = ((hi >> 20) & 0x7ff) - 1023;
        const double sc = __hiloint2double((1023 - ex) << 20, 0);   // 2^-ex
        a0 *= sc; a1 *= sc; a2 *= sc; a3 *= sc; a4 *= sc;
        kacc += ex;
    };

    if (dir == 0) {
        // ---------------- forward alpha: t = 0 .. m-1 ----------------
        const int2 cc = ((const int2*)lab)[l];                        // labels 2l, 2l+1
        skip1d = ((l > 0) && (cc.x != lab[2 * l - 1])) ? 1.0 : 0.0;
        skip3d = (cc.y != cc.x) ? 1.0 : 0.0;

        stage_chunk(0, 1);
        __builtin_amdgcn_s_waitcnt(0x0f70);     // vmcnt(0)

        {   // t = 0 init
            const float2 ep0 = eprow[l];
            a0 = (l == 0) ? (double)ebl[0] : 0.0;
            a1 = (l == 0) ? (double)ep0.x : 0.0;
        }

        const int nsteps = m - 1;               // t = 1 .. m-1
        const int nch = (nsteps + CH - 1) / CH;
        for (int c = 0; c < nch; ++c) {
            const int cb = c & 1;
            const bool more = (c + 1 < nch);
            if (more) stage_chunk(cb ^ 1, 1 + CH * (c + 1));
            __builtin_amdgcn_sched_barrier(0);
            const int t0 = 1 + CH * c;
            if (t0 + CH <= m) {
                // full chunk: branch-free body, distance-3 register rotation
                double e1R[4], e2R[4], ebR[4];
#pragma unroll
                for (int p = 0; p < 3; ++p) {
                    const float2 ep = ebuf[cb][p][l];
                    e1R[p] = (double)ep.x; e2R[p] = (double)ep.y;
                    ebR[p] = (double)ebl[t0 + p];
                }
#pragma unroll
                for (int j = 0; j < CH; ++j) {
                    const int jn = (j + 3 < CH) ? (j + 3) : (CH - 1);
                    const float2 epn = ebuf[cb][jn][l];
                    const float ebn = ebl[t0 + jn];
                    step(e1R[j & 3], e2R[j & 3], ebR[j & 3]);
                    e1R[(j + 3) & 3] = (double)epn.x;
                    e2R[(j + 3) & 3] = (double)epn.y;
                    ebR[(j + 3) & 3] = (double)ebn;
                }
            } else {
                // tail chunk (once): predicated, plain LDS reads
#pragma unroll
                for (int j = 0; j < CH; ++j) {
                    if (t0 + j < m) {
                        const float2 ep = ebuf[cb][j][l];
                        step((double)ep.x, (double)ep.y, (double)ebl[t0 + j]);
                    }
                }
            }
            renorm();
            if (more) __builtin_amdgcn_s_waitcnt(0x0f70);
            __builtin_amdgcn_sched_barrier(0);
        }

        double* av = alphavec + b * 264;
        av[4 * l + 0] = a0; av[4 * l + 1] = a1;
        av[4 * l + 2] = a2; av[4 * l + 3] = a3;
        if (l == 63) av[256] = a4;
        if (l == 0) kaccs[2 * b + 0] = kacc;
    } else {
        // ---------------- backward beta: t = dlen-1 .. m (reversed states r=256-s) ----
        const int2 c2 = ((const int2*)lab)[63 - l];    // (lab[126-2l], lab[127-2l])
        const int labL = (l > 0) ? lab[128 - 2 * l] : -1;
        skip1d = ((l > 0) && (labL != c2.y)) ? 1.0 : 0.0;   // r=4l+1
        skip3d = (c2.y != c2.x) ? 1.0 : 0.0;                // r=4l+3

        stage_chunk(0, dlen - 1 - CH);          // rows [dlen-1-CH, dlen-2]
        __builtin_amdgcn_s_waitcnt(0x0f70);

        {   // init at t = dlen-1: beta = e * [s==2len || s==2len-1],  s = 256-r
            const float2 epi = eprow[(size_t)(dlen - 1) * 64 + (63 - l)];
            const double ebi = (double)ebl[dlen - 1];
            const int s0 = 256 - 4 * l;
            a0 = (s0 == 2 * len     || s0 == 2 * len - 1) ? ebi : 0.0;
            a1 = (s0 - 1 == 2 * len || s0 - 1 == 2 * len - 1) ? (double)epi.y : 0.0;
            a2 = (s0 - 2 == 2 * len || s0 - 2 == 2 * len - 1) ? ebi : 0.0;
            a3 = (s0 - 3 == 2 * len || s0 - 3 == 2 * len - 1) ? (double)epi.x : 0.0;
            a4 = 0.0;                            // lane63's r=256 is s=0, never terminal
        }

        const int nsteps = dlen - 1 - m;        // t = dlen-2 .. m
        const int nch = (nsteps + CH - 1) / CH;
        for (int c = 0; c < nch; ++c) {
            const int cb = c & 1;
            const bool more = (c + 1 < nch);
            const int thi = dlen - 2 - CH * c;
            const int tlo = thi - CH + 1;
            if (more) stage_chunk(cb ^ 1, tlo - CH);
            __builtin_amdgcn_sched_barrier(0);
            if (tlo >= m) {
                // full chunk: jj ascending = t descending; em1 = ep.y, em3 = ep.x
                double e1R[4], e2R[4], ebR[4];
#pragma unroll
                for (int p = 0; p < 3; ++p) {
                    const float2 ep = ebuf[cb][CH - 1 - p][63 - l];
                    e1R[p] = (double)ep.y; e2R[p] = (double)ep.x;
                    ebR[p] = (double)ebl[thi - p];
                }
#pragma unroll
                for (int jj = 0; jj < CH; ++jj) {
                    const int jnn = (jj + 3 < CH) ? (jj + 3) : (CH - 1);
                    const float2 epn = ebuf[cb][CH - 1 - jnn][63 - l];
                    const float ebn = ebl[thi - jnn];
                    step(e1R[jj & 3], e2R[jj & 3], ebR[jj & 3]);
                    e1R[(jj + 3) & 3] = (double)epn.y;
                    e2R[(jj + 3) & 3] = (double)epn.x;
                    ebR[(jj + 3) & 3] = (double)ebn;
                }
            } else {
                // tail chunk (once): predicated
#pragma unroll
                for (int jj = 0; jj < CH; ++jj) {
                    const int j = CH - 1 - jj;
                    const int t = tlo + j;
                    if (t >= m) {
                        const float2 ep = ebuf[cb][j][63 - l];
                        step((double)ep.y, (double)ep.x, (double)ebl[t]);
                    }
                }
            }
            renorm();
            if (more) __builtin_amdgcn_s_waitcnt(0x0f70);
            __builtin_amdgcn_sched_barrier(0);
        }

        double* bv = betavec + b * 264;               // natural s order
        bv[256 - 4 * l] = a0; bv[255 - 4 * l] = a1;
        bv[254 - 4 * l] = a2; bv[253 - 4 * l] = a3;
        if (l == 63) bv[0] = a4;
        if (l == 0) { bv[257] = 0.0; bv[258] = 0.0; kaccs[2 * b + 1] = kacc; }
    }
}

// ---------------- Kernel 3: combine alpha(m-1) x T x beta(m), mean over b ----------
// Single block, 4 waves; wave w handles b = w, w+4, ..., w+28.
__global__ __launch_bounds__(256) void combine_kernel(const double* __restrict__ alphavec,
                                                      const double* __restrict__ betavec,
                                                      const long long* __restrict__ kaccs,
                                                      const int* __restrict__ labels,
                                                      float* __restrict__ out) {
    const int wave = threadIdx.x >> 6;
    const int l = threadIdx.x & 63;
    float acc = 0.f;

    for (int b = wave; b < B_DIM; b += 4) {
        const double* A = alphavec + b * 264;
        const double* Bv = betavec + b * 264;
        const int* lab = labels + b * L_DIM;

        const double a0 = A[4 * l], a1 = A[4 * l + 1], a2 = A[4 * l + 2], a3 = A[4 * l + 3];
        const double b0 = Bv[4 * l], b1 = Bv[4 * l + 1], b2 = Bv[4 * l + 2];
        const double b3 = Bv[4 * l + 3], b4 = Bv[4 * l + 4], b5 = Bv[4 * l + 5];
        const double sk1 = (lab[2 * l + 1] != lab[2 * l]) ? 1.0 : 0.0;        // into 4l+3
        const int labn = (l < 63) ? lab[2 * l + 2] : -1;
        const double sk3 = ((l < 63) && (labn != lab[2 * l + 1])) ? 1.0 : 0.0; // into 4l+5

        double s = a0 * (b0 + b1)
                 + a1 * (b1 + b2 + sk1 * b3)
                 + a2 * (b2 + b3)
                 + a3 * (b3 + b4 + sk3 * b5);
        if (l == 63) s += A[256] * Bv[256];

#pragma unroll
        for (int off = 32; off >= 1; off >>= 1)
            s += __shfl_xor(s, off, 64);

        if (l == 0) {
            const long long k = kaccs[2 * b] + kaccs[2 * b + 1];
            const long long vb = __double_as_longlong(s);
            const int ve = (int)((vb >> 52) & 0x7ff) - 1023;
            const double mant = __longlong_as_double(
                (vb & 0x000FFFFFFFFFFFFFLL) | (1023LL << 52));        // [1,2)
            const double l2 = (double)__log2f((float)mant) + (double)ve + (double)k;
            acc += (float)(-l2 * 0.6931471805599453);
        }
    }

    __shared__ float part[4];
    if (l == 0) part[wave] = acc;
    __syncthreads();
    if (threadIdx.x == 0)
        out[0] = (part[0] + part[1] + part[2] + part[3]) * (1.0f / B_DIM);
}

extern "C" void kernel_launch(void* const* d_in, const int* in_sizes, int n_in,
                              void* d_out, int out_size, void* d_ws, size_t ws_size,
                              hipStream_t stream) {
    const int*   labels       = (const int*)d_in[0];
    const float* data         = (const float*)d_in[1];
    const int*   label_length = (const int*)d_in[2];
    const int*   data_length  = (const int*)d_in[3];
    float*       out          = (float*)d_out;

    char* ws = (char*)d_ws;
    float2*    epair    = (float2*)(ws + WS_EPAIR);
    float*     eblank   = (float*)(ws + WS_EBLANK);
    double*    alphavec = (double*)(ws + WS_ALPHA);
    double*    betavec  = (double*)(ws + WS_BETA);
    long long* kaccs    = (long long*)(ws + WS_KACC);

    const int rows = T_DIM * B_DIM;
    emit_kernel<<<rows / 4, 256, 0, stream>>>(data, labels, data_length, epair, eblank);
    dp_kernel<<<2 * B_DIM, 64, 0, stream>>>(epair, eblank, labels, label_length,
                                            data_length, alphavec, betavec, kaccs);
    combine_kernel<<<1, 256, 0, stream>>>(alphavec, betavec, kaccs, labels, out);
}